// Round 3
// baseline (6315.637 us; speedup 1.0000x reference)
//
#include <hip/hip_runtime.h>
#include <cmath>
#include <cstdint>
#include <cfloat>

// ---------------------------------------------------------------------------
// CenterNet head, MI355X. Round 3: f32-quantized selection domain.
// 3x3 convs: f32 accum (1-2 ulp agreement with any decent f32 impl; propagates
//            ~1e-9 into logits, far below ulp(-4.6)=4.8e-7).
// 1x1 cls:   f64 accum -> correctly-rounded f32 logits.
// Selection (NMS + per-class topk + global topk): on f32 logits, ties by index
//            -> reproduces lax.top_k tie behavior of an f32 reference.
// ---------------------------------------------------------------------------

#define CN_B   16
#define CN_H   128
#define CN_W   128
#define CN_HW  16384
#define CN_CLS 80
#define CN_K   100
#define NEG_SENT (-3.402823466e+38f)

// ---------------------------------------------------------------------------
// 3x3 conv, pad 1, + bias (+ optional ReLU). in [Bc,CI,H,W], w [CO,CI,3,3].
// Block: 256 thr = 2 rows x 128 cols, each thread: 1 pixel x 8 output chans.
// grid.x = Bc * (H/2) * (CO/8). Batch index is chunk-local.
// ---------------------------------------------------------------------------
template<int CI>
__global__ __launch_bounds__(256) void conv3x3_k(
    const float* __restrict__ in, const float* __restrict__ wgt,
    const float* __restrict__ bias, float* __restrict__ out, int CO)
{
    constexpr int CC = 4;  // input-channel chunk staged in LDS
    const int bid  = blockIdx.x;
    const int cob  = CO >> 3;
    const int co0  = (bid % cob) * 8;
    const int tmp  = bid / cob;
    const int h0   = (tmp % (CN_H / 2)) * 2;
    const int b    = tmp / (CN_H / 2);

    __shared__ float lin[CC][4][132];  // rows h0-1..h0+2, cols -1..128 at idx+1
    __shared__ float lw[CC][9][8];

    const int t   = threadIdx.x;
    const int col = t & 127;
    const int r   = t >> 7;            // 0..1
    const int h   = h0 + r;

    float acc[8];
#pragma unroll
    for (int o = 0; o < 8; ++o) acc[o] = 0.f;

    for (int ci0 = 0; ci0 < CI; ci0 += CC) {
        for (int e = t; e < CC * 4 * 130; e += 256) {
            int cc  = e / 520;
            int rem = e % 520;
            int rr  = rem / 130;
            int cx  = rem % 130;
            int srow = h0 - 1 + rr;
            int scol = cx - 1;
            float v = 0.f;
            if ((unsigned)srow < (unsigned)CN_H && (unsigned)scol < (unsigned)CN_W)
                v = in[(((size_t)b * CI + ci0 + cc) * CN_H + srow) * CN_W + scol];
            lin[cc][rr][cx] = v;
        }
        for (int e = t; e < CC * 9 * 8; e += 256) {
            int cc  = e / 72;
            int rem = e % 72;
            int tap = rem / 8;
            int o   = rem % 8;
            lw[cc][tap][o] = wgt[(((size_t)(co0 + o)) * CI + ci0 + cc) * 9 + tap];
        }
        __syncthreads();
#pragma unroll
        for (int cc = 0; cc < CC; ++cc) {
#pragma unroll
            for (int kh = 0; kh < 3; ++kh) {
#pragma unroll
                for (int kw = 0; kw < 3; ++kw) {
                    float v = lin[cc][r + kh][col + kw];
#pragma unroll
                    for (int o = 0; o < 8; ++o)
                        acc[o] = fmaf(v, lw[cc][kh * 3 + kw][o], acc[o]);
                }
            }
        }
        __syncthreads();
    }
#pragma unroll
    for (int o = 0; o < 8; ++o) {
        float v = acc[o] + bias[co0 + o];
        v = v > 0.f ? v : 0.f;   // both 3x3 layers of both branches use ReLU
        out[(((size_t)b * CO + co0 + o) * CN_H + h) * CN_W + col] = v;
    }
}

// ---------------------------------------------------------------------------
// 1x1 conv for cls head: 128 -> 80, f64 accumulate, + bias, round to f32.
// grid (Bc*64, 5): blockIdx.y picks a tile of 16 output channels. b chunk-local.
// ---------------------------------------------------------------------------
__global__ __launch_bounds__(256) void conv1x1_cls_k(
    const float* __restrict__ h2, const float* __restrict__ wgt,
    const float* __restrict__ bias, float* __restrict__ logits)
{
    constexpr int CI = 128;
    const int p  = (blockIdx.x % 64) * 256 + threadIdx.x;
    const int b  = blockIdx.x / 64;
    const int o0 = blockIdx.y * 16;

    __shared__ double lw[CI][16];
    for (int e = threadIdx.x; e < CI * 16; e += 256) {
        int ci = e / 16, o = e % 16;
        lw[ci][o] = (double)wgt[(size_t)(o0 + o) * CI + ci];
    }
    __syncthreads();

    double acc[16];
#pragma unroll
    for (int o = 0; o < 16; ++o) acc[o] = 0.0;

    for (int ci = 0; ci < CI; ++ci) {
        double v = (double)h2[((size_t)b * CI + ci) * CN_HW + p];
#pragma unroll
        for (int o = 0; o < 16; ++o) acc[o] += v * lw[ci][o];
    }
#pragma unroll
    for (int o = 0; o < 16; ++o)
        logits[((size_t)b * CN_CLS + o0 + o) * CN_HW + p] =
            (float)(acc[o] + (double)bias[o0 + o]);
}

// ---------------------------------------------------------------------------
// 1x1 conv for wh head: 64 -> 4, f32, bias, ReLU, * 16. grid Bc*64. b local.
// ---------------------------------------------------------------------------
__global__ __launch_bounds__(256) void conv1x1_wh_k(
    const float* __restrict__ g2, const float* __restrict__ wgt,
    const float* __restrict__ bias, float* __restrict__ wh)
{
    constexpr int CI = 64;
    const int p = (blockIdx.x % 64) * 256 + threadIdx.x;
    const int b = blockIdx.x / 64;

    __shared__ float lw[CI][4];
    for (int e = threadIdx.x; e < CI * 4; e += 256) {
        int ci = e / 4, o = e % 4;
        lw[ci][o] = wgt[(size_t)o * CI + ci];
    }
    __syncthreads();

    float acc[4] = {0.f, 0.f, 0.f, 0.f};
    for (int ci = 0; ci < CI; ++ci) {
        float v = g2[((size_t)b * CI + ci) * CN_HW + p];
#pragma unroll
        for (int o = 0; o < 4; ++o) acc[o] = fmaf(v, lw[ci][o], acc[o]);
    }
#pragma unroll
    for (int o = 0; o < 4; ++o) {
        float v = acc[o] + bias[o];
        v = v > 0.f ? v : 0.f;
        wh[((size_t)b * 4 + o) * CN_HW + p] = v * 16.0f;
    }
}

// ---------------------------------------------------------------------------
// Fused 3x3 NMS + per-class top-100, all on f32 LOGITS (monotone == sigmoid
// ranking; equal f32 logits == ref's f32-sigmoid ties, broken by index).
// Suppressed pixels -> NEG_SENT (ref's zeros: below every kept value, ties by
// index among themselves). One block per (b_local, class). LDS 64 KB.
// ---------------------------------------------------------------------------
__global__ __launch_bounds__(256) void nms_topk_k(
    const float* __restrict__ logits,
    float* __restrict__ pc_logit,    // [B, 8000] at bg*8000 + c*100 + k
    int*   __restrict__ pc_ind,      // same layout
    int b0)
{
    __shared__ float sc[CN_HW];
    __shared__ float rv[4];
    __shared__ int   ri[4];

    const int bc = blockIdx.x;               // b_local*80 + c
    const int bl = bc / CN_CLS;
    const int c  = bc % CN_CLS;
    const int bg = b0 + bl;
    const int t  = threadIdx.x;
    const float* L = logits + (size_t)bc * CN_HW;

    for (int p = t; p < CN_HW; p += 256) sc[p] = L[p];
    __syncthreads();

    // local-max flags on f32 logits (strict >; ties keep both, like hmax==heat)
    unsigned long long flags = 0;
    for (int k = 0; k < 64; ++k) {
        const int p   = t + 256 * k;
        const int row = p >> 7, cl = p & 127;
        const float c0 = sc[p];
        bool mx = true;
#pragma unroll
        for (int dr = -1; dr <= 1; ++dr)
#pragma unroll
            for (int dc = -1; dc <= 1; ++dc) {
                if (dr == 0 && dc == 0) continue;
                int rr = row + dr, cc2 = cl + dc;
                if ((unsigned)rr < (unsigned)CN_H && (unsigned)cc2 < (unsigned)CN_W)
                    if (sc[(rr << 7) + cc2] > c0) mx = false;
            }
        if (mx) flags |= 1ull << k;
    }
    __syncthreads();
    for (int k = 0; k < 64; ++k) {
        const int p = t + 256 * k;
        if (!((flags >> k) & 1)) sc[p] = NEG_SENT;
    }
    __syncthreads();

    // 100 x argmax with index tie-break
    for (int it = 0; it < CN_K; ++it) {
        float bv = -INFINITY;
        int   bi = 0x7fffffff;
        for (int k = 0; k < 64; ++k) {
            const int p = t + 256 * k;
            const float v = sc[p];
            if (v > bv || (v == bv && p < bi)) { bv = v; bi = p; }
        }
#pragma unroll
        for (int off = 32; off; off >>= 1) {
            float ov = __shfl_down(bv, off);
            int   oi = __shfl_down(bi, off);
            if (ov > bv || (ov == bv && oi < bi)) { bv = ov; bi = oi; }
        }
        const int wid = t >> 6;
        if ((t & 63) == 0) { rv[wid] = bv; ri[wid] = bi; }
        __syncthreads();
        if (t == 0) {
            for (int wv = 1; wv < 4; ++wv)
                if (rv[wv] > bv || (rv[wv] == bv && ri[wv] < bi)) { bv = rv[wv]; bi = ri[wv]; }
            pc_logit[(size_t)bg * 8000 + c * CN_K + it] = bv;
            pc_ind  [(size_t)bg * 8000 + c * CN_K + it] = bi;
            sc[bi] = -INFINITY;
        }
        __syncthreads();
    }
}

// ---------------------------------------------------------------------------
// Global top-100 over 8000 candidates (f32 logits, index tie-break) + sigmoid
// + bbox gather + output. One block per b.
// ---------------------------------------------------------------------------
__global__ __launch_bounds__(256) void global_out_k(
    const float* __restrict__ pc_logit, const int* __restrict__ pc_ind,
    const float* __restrict__ wh, float* __restrict__ out)
{
    constexpr int N = CN_CLS * CN_K;  // 8000
    __shared__ float sc[N];
    __shared__ float rv[4];
    __shared__ int   ri[4];
    __shared__ int   sel[CN_K];
    __shared__ float selv[CN_K];

    const int b = blockIdx.x;
    const int t = threadIdx.x;

    for (int p = t; p < N; p += 256) sc[p] = pc_logit[(size_t)b * N + p];
    __syncthreads();

    for (int it = 0; it < CN_K; ++it) {
        float bv = -INFINITY;
        int   bi = 0x7fffffff;
        for (int p = t; p < N; p += 256) {
            const float v = sc[p];
            if (v > bv || (v == bv && p < bi)) { bv = v; bi = p; }
        }
#pragma unroll
        for (int off = 32; off; off >>= 1) {
            float ov = __shfl_down(bv, off);
            int   oi = __shfl_down(bi, off);
            if (ov > bv || (ov == bv && oi < bi)) { bv = ov; bi = oi; }
        }
        const int wid = t >> 6;
        if ((t & 63) == 0) { rv[wid] = bv; ri[wid] = bi; }
        __syncthreads();
        if (t == 0) {
            for (int wv = 1; wv < 4; ++wv)
                if (rv[wv] > bv || (rv[wv] == bv && ri[wv] < bi)) { bv = rv[wv]; bi = ri[wv]; }
            sel[it]  = bi;
            selv[it] = bv;
            sc[bi]   = -INFINITY;
        }
        __syncthreads();
    }

    if (t < CN_K) {
        const int flat = sel[t];
        const int cls  = flat / CN_K;
        const int ind  = pc_ind[(size_t)b * N + flat];
        // score: correctly-rounded sigmoid of the f32 logit.
        // NEG_SENT -> exp(+huge)=inf -> 0.0, matching ref's zeroed heat.
        const float score = (float)(1.0 / (1.0 + exp(-(double)selv[t])));
        const float ys = (float)(ind >> 7) * 4.0f;
        const float xs = (float)(ind & 127) * 4.0f;
        const float wl = wh[((size_t)b * 4 + 0) * CN_HW + ind];
        const float wt = wh[((size_t)b * 4 + 1) * CN_HW + ind];
        const float wr = wh[((size_t)b * 4 + 2) * CN_HW + ind];
        const float wb = wh[((size_t)b * 4 + 3) * CN_HW + ind];
        float* row = out + ((size_t)b * CN_K + t) * 6;
        row[0] = xs - wl;
        row[1] = ys - wt;
        row[2] = xs + wr;
        row[3] = ys + wb;
        row[4] = score;
        row[5] = (float)cls;
        out[CN_B * CN_K * 6 + b * CN_K + t] = (score > 0.01f) ? 1.0f : 0.0f;
    }
}

// ---------------------------------------------------------------------------
extern "C" void kernel_launch(void* const* d_in, const int* in_sizes, int n_in,
                              void* d_out, int out_size, void* d_ws, size_t ws_size,
                              hipStream_t stream)
{
    (void)in_sizes; (void)n_in; (void)out_size;

    const float* x      = (const float*)d_in[0];
    const float* cls_w1 = (const float*)d_in[1];
    const float* cls_b1 = (const float*)d_in[2];
    const float* cls_w2 = (const float*)d_in[3];
    const float* cls_b2 = (const float*)d_in[4];
    const float* cls_w3 = (const float*)d_in[5];
    const float* cls_b3 = (const float*)d_in[6];
    const float* wh_w1  = (const float*)d_in[7];
    const float* wh_b1  = (const float*)d_in[8];
    const float* wh_w2  = (const float*)d_in[9];
    const float* wh_b2  = (const float*)d_in[10];
    const float* wh_w3  = (const float*)d_in[11];
    const float* wh_b3  = (const float*)d_in[12];
    float* out = (float*)d_out;

    // Workspace overlay, per batch-chunk of Bc images:
    //   regionA: max(g1 4.19M, h1 8.39M, logits-f32 5.24M) = 8,388,608 B
    //   regionB: max(g2 4.19M, h2 8.39M)                    = 8,388,608 B
    //   persistent: whbuf 4,194,304 + pc_logit 512,000 + pc_ind 512,000
    const size_t PERA = 8388608u, PERB = 8388608u;
    const size_t PERS = 4194304u + 512000u + 512000u;
    int Bc = 1;
    {
        const int cand[5] = {16, 8, 4, 2, 1};
        for (int i = 0; i < 5; ++i) {
            if ((size_t)cand[i] * (PERA + PERB) + PERS <= ws_size) { Bc = cand[i]; break; }
        }
    }

    char* ws = (char*)d_ws;
    char*  regA  = ws;
    char*  regB  = ws + (size_t)Bc * PERA;
    float* whbuf = (float*)(ws + (size_t)Bc * (PERA + PERB));
    float* pc_s  = (float*)((char*)whbuf + 4194304u);
    int*   pc_i  = (int*)((char*)pc_s + 512000u);

    dim3 blk(256);

    for (int b0 = 0; b0 < CN_B; b0 += Bc) {
        const float* xc = x + (size_t)b0 * 64 * CN_HW;
        float* g1     = (float*)regA;
        float* g2     = (float*)regB;
        float* h1     = (float*)regA;
        float* h2     = (float*)regB;
        float* logits = (float*)regA;
        float* whc    = whbuf + (size_t)b0 * 4 * CN_HW;

        // wh branch (f32)
        conv3x3_k<64><<<dim3(Bc * 64 * 8), blk, 0, stream>>>(xc, wh_w1, wh_b1, g1, 64);
        conv3x3_k<64><<<dim3(Bc * 64 * 8), blk, 0, stream>>>(g1, wh_w2, wh_b2, g2, 64);
        conv1x1_wh_k<<<dim3(Bc * 64), blk, 0, stream>>>(g2, wh_w3, wh_b3, whc);

        // cls branch: f32 3x3 convs, f64-accum 1x1 -> correctly-rounded f32 logits
        conv3x3_k<64><<<dim3(Bc * 64 * 16), blk, 0, stream>>>(xc, cls_w1, cls_b1, h1, 128);
        conv3x3_k<128><<<dim3(Bc * 64 * 16), blk, 0, stream>>>(h1, cls_w2, cls_b2, h2, 128);
        conv1x1_cls_k<<<dim3(Bc * 64, 5), blk, 0, stream>>>(h2, cls_w3, cls_b3, logits);

        // per-class selection for this chunk (f32 logit domain)
        nms_topk_k<<<dim3(Bc * CN_CLS), blk, 0, stream>>>(logits, pc_s, pc_i, b0);
    }

    global_out_k<<<dim3(CN_B), blk, 0, stream>>>(pc_s, pc_i, whbuf, out);
}

// Round 4
// 3346.097 us; speedup vs baseline: 1.8875x; 1.8875x over previous
//
#include <hip/hip_runtime.h>
#include <cmath>
#include <cstdint>
#include <cfloat>

// ---------------------------------------------------------------------------
// CenterNet head, MI355X. Round 4: bitonic top-k + high-reuse conv tiles.
// Numerics contract (proven in R3, absmax 0.0):
//   - 3x3 convs: f32 fmaf chains, EXACT order (ci0 asc, cc, kh, kw) preserved.
//   - 1x1 cls: f64 accum -> correctly-rounded f32 logits.
//   - Selection on f32 logits, ties by lowest index (== lax.top_k on f32 ref).
// ---------------------------------------------------------------------------

#define CN_B   16
#define CN_H   128
#define CN_W   128
#define CN_HW  16384
#define CN_CLS 80
#define CN_K   100
#define NEG_SENT (-3.402823466e+38f)

__device__ __forceinline__ unsigned ordf(float v) {
    unsigned b = __float_as_uint(v);
    return (b >> 31) ? ~b : (b | 0x80000000u);
}
__device__ __forceinline__ float unordf(unsigned o) {
    return __uint_as_float((o >> 31) ? (o & 0x7fffffffu) : ~o);
}

// ---------------------------------------------------------------------------
// 3x3 conv, pad 1, bias + ReLU. Tile: 8 rows x 128 cols x 16 out-chans.
// 256 thr = 2 rows x 128 cols; each thread: 4 px (rows r2+{0,2,4,6}) x 16 oc.
// grid.x = Bc * 16 * (CO/16). Bitwise-identical accumulation order to R3.
// ---------------------------------------------------------------------------
template<int CI>
__global__ __launch_bounds__(256) void conv3x3_k(
    const float* __restrict__ in, const float* __restrict__ wgt,
    const float* __restrict__ bias, float* __restrict__ out, int CO)
{
    constexpr int CC = 4;
    const int bid = blockIdx.x;
    const int cob = CO >> 4;
    const int co0 = (bid % cob) * 16;
    const int tmp = bid / cob;
    const int h0  = (tmp & 15) * 8;
    const int b   = tmp >> 4;

    __shared__ float lin[CC][10][132];   // rows h0-1 .. h0+8, cols -1..128 @+1
    __shared__ float lw[CC][9][16];

    const int t   = threadIdx.x;
    const int col = t & 127;
    const int r2  = t >> 7;              // 0..1

    float acc[4][16];
#pragma unroll
    for (int px = 0; px < 4; ++px)
#pragma unroll
        for (int o = 0; o < 16; ++o) acc[px][o] = 0.f;

    for (int ci0 = 0; ci0 < CI; ci0 += CC) {
        for (int e = t; e < CC * 10 * 130; e += 256) {
            int cc  = e / 1300;
            int rem = e % 1300;
            int rr  = rem / 130;
            int cx  = rem % 130;
            int srow = h0 - 1 + rr;
            int scol = cx - 1;
            float v = 0.f;
            if ((unsigned)srow < (unsigned)CN_H && (unsigned)scol < (unsigned)CN_W)
                v = in[(((size_t)b * CI + ci0 + cc) * CN_H + srow) * CN_W + scol];
            lin[cc][rr][cx] = v;
        }
        for (int e = t; e < CC * 9 * 16; e += 256) {
            int cc  = e / 144;
            int rem = e % 144;
            int tap = rem / 16;
            int o   = rem % 16;
            lw[cc][tap][o] = wgt[(((size_t)(co0 + o)) * CI + ci0 + cc) * 9 + tap];
        }
        __syncthreads();
        for (int cc = 0; cc < CC; ++cc) {
#pragma unroll
            for (int kh = 0; kh < 3; ++kh) {
#pragma unroll
                for (int kw = 0; kw < 3; ++kw) {
#pragma unroll
                    for (int px = 0; px < 4; ++px) {
                        float v = lin[cc][r2 + 2 * px + kh][col + kw];
#pragma unroll
                        for (int o = 0; o < 16; ++o)
                            acc[px][o] = fmaf(v, lw[cc][kh * 3 + kw][o], acc[px][o]);
                    }
                }
            }
        }
        __syncthreads();
    }
#pragma unroll
    for (int px = 0; px < 4; ++px) {
        const int h = h0 + r2 + 2 * px;
#pragma unroll
        for (int o = 0; o < 16; ++o) {
            float v = acc[px][o] + bias[co0 + o];
            v = v > 0.f ? v : 0.f;
            out[(((size_t)b * CO + co0 + o) * CN_H + h) * CN_W + col] = v;
        }
    }
}

// ---------------------------------------------------------------------------
// 1x1 cls: 128 -> 80, f64 accumulate, bias, round to f32. (unchanged from R3)
// ---------------------------------------------------------------------------
__global__ __launch_bounds__(256) void conv1x1_cls_k(
    const float* __restrict__ h2, const float* __restrict__ wgt,
    const float* __restrict__ bias, float* __restrict__ logits)
{
    constexpr int CI = 128;
    const int p  = (blockIdx.x % 64) * 256 + threadIdx.x;
    const int b  = blockIdx.x / 64;
    const int o0 = blockIdx.y * 16;

    __shared__ double lw[CI][16];
    for (int e = threadIdx.x; e < CI * 16; e += 256) {
        int ci = e / 16, o = e % 16;
        lw[ci][o] = (double)wgt[(size_t)(o0 + o) * CI + ci];
    }
    __syncthreads();

    double acc[16];
#pragma unroll
    for (int o = 0; o < 16; ++o) acc[o] = 0.0;

    for (int ci = 0; ci < CI; ++ci) {
        double v = (double)h2[((size_t)b * CI + ci) * CN_HW + p];
#pragma unroll
        for (int o = 0; o < 16; ++o) acc[o] += v * lw[ci][o];
    }
#pragma unroll
    for (int o = 0; o < 16; ++o)
        logits[((size_t)b * CN_CLS + o0 + o) * CN_HW + p] =
            (float)(acc[o] + (double)bias[o0 + o]);
}

// ---------------------------------------------------------------------------
// 1x1 wh: 64 -> 4, f32, bias, ReLU, *16. (unchanged from R3)
// ---------------------------------------------------------------------------
__global__ __launch_bounds__(256) void conv1x1_wh_k(
    const float* __restrict__ g2, const float* __restrict__ wgt,
    const float* __restrict__ bias, float* __restrict__ wh)
{
    constexpr int CI = 64;
    const int p = (blockIdx.x % 64) * 256 + threadIdx.x;
    const int b = blockIdx.x / 64;

    __shared__ float lw[CI][4];
    for (int e = threadIdx.x; e < CI * 4; e += 256) {
        int ci = e / 4, o = e % 4;
        lw[ci][o] = wgt[(size_t)o * CI + ci];
    }
    __syncthreads();

    float acc[4] = {0.f, 0.f, 0.f, 0.f};
    for (int ci = 0; ci < CI; ++ci) {
        float v = g2[((size_t)b * CI + ci) * CN_HW + p];
#pragma unroll
        for (int o = 0; o < 4; ++o) acc[o] = fmaf(v, lw[ci][o], acc[o]);
    }
#pragma unroll
    for (int o = 0; o < 4; ++o) {
        float v = acc[o] + bias[o];
        v = v > 0.f ? v : 0.f;
        wh[((size_t)b * 4 + o) * CN_HW + p] = v * 16.0f;
    }
}

// ---------------------------------------------------------------------------
// NMS + per-class top-100 via candidate compaction + bitonic sort.
// Key u64 = (ordered_f32_logit << 32) | ~index  -> desc sort == (value desc,
// index asc), exactly the R3-proven tie semantics. Fallback to the R3 argmax
// loop (global reads, flag/removed reg masks) if M<100 or M>2048.
// One block per (b_local, class). LDS ~16.5 KB.
// ---------------------------------------------------------------------------
#define NMS_CAP 2048

__global__ __launch_bounds__(256) void nms_topk_k(
    const float* __restrict__ logits,
    float* __restrict__ pc_logit,    // [B,8000] @ bg*8000 + c*100 + k
    int*   __restrict__ pc_ind,
    int b0)
{
    __shared__ unsigned long long cand[NMS_CAP];
    __shared__ int   cnt;
    __shared__ float rv[4];
    __shared__ int   ri[4];
    __shared__ int   pick;

    const int bc = blockIdx.x;
    const int bl = bc / CN_CLS;
    const int c  = bc % CN_CLS;
    const int bg = b0 + bl;
    const int t  = threadIdx.x;
    const float* L = logits + (size_t)bc * CN_HW;

    if (t == 0) cnt = 0;
    __syncthreads();

    // local-max flags from global (maps are L2-resident)
    unsigned long long flags = 0;
    for (int k = 0; k < 64; ++k) {
        const int p   = t + 256 * k;
        const int row = p >> 7, cl = p & 127;
        const float c0 = L[p];
        bool mx = true;
#pragma unroll
        for (int dr = -1; dr <= 1; ++dr)
#pragma unroll
            for (int dc = -1; dc <= 1; ++dc) {
                if (dr == 0 && dc == 0) continue;
                int rr = row + dr, cc2 = cl + dc;
                if ((unsigned)rr < (unsigned)CN_H && (unsigned)cc2 < (unsigned)CN_W)
                    if (L[(rr << 7) + cc2] > c0) mx = false;
            }
        if (mx) flags |= 1ull << k;
    }

    // compact candidates
    {
        unsigned long long f = flags;
        while (f) {
            int k = __ffsll((long long)f) - 1;
            f &= f - 1;
            const int p = t + 256 * k;
            const int slot = atomicAdd(&cnt, 1);
            if (slot < NMS_CAP) {
                const float v = L[p];
                cand[slot] = ((unsigned long long)ordf(v) << 32) | (unsigned)(~p);
            }
        }
    }
    __syncthreads();
    const int M = cnt;

    if (M >= CN_K && M <= NMS_CAP) {
        int P = 128;
        while (P < M) P <<= 1;
        for (int i = M + t; i < P; i += 256) cand[i] = 0ull;
        __syncthreads();
        for (int k = 2; k <= P; k <<= 1) {
            for (int j = k >> 1; j > 0; j >>= 1) {
                for (int n = t; n < (P >> 1); n += 256) {
                    const int i = ((n & ~(j - 1)) << 1) | (n & (j - 1));
                    const int m = i | j;
                    const unsigned long long a = cand[i], bqq = cand[m];
                    const bool up = ((i & k) == 0);
                    if (up ? (a < bqq) : (a > bqq)) { cand[i] = bqq; cand[m] = a; }
                }
                __syncthreads();
            }
        }
        if (t < CN_K) {
            const unsigned long long key = cand[t];
            const int p = (int)(~(unsigned)key) & 0xFFFF;
            pc_logit[(size_t)bg * 8000 + c * CN_K + t] = unordf((unsigned)(key >> 32));
            pc_ind  [(size_t)bg * 8000 + c * CN_K + t] = p;
        }
    } else {
        // fallback: R3-equivalent iterative argmax (suppressed -> NEG_SENT)
        unsigned long long removed = 0;
        for (int it = 0; it < CN_K; ++it) {
            float bv = -INFINITY;
            int   bi = 0x7fffffff;
            for (int k = 0; k < 64; ++k) {
                if ((removed >> k) & 1) continue;
                const int p = t + 256 * k;
                const float v = ((flags >> k) & 1) ? L[p] : NEG_SENT;
                if (v > bv || (v == bv && p < bi)) { bv = v; bi = p; }
            }
#pragma unroll
            for (int off = 32; off; off >>= 1) {
                float ov = __shfl_down(bv, off);
                int   oi = __shfl_down(bi, off);
                if (ov > bv || (ov == bv && oi < bi)) { bv = ov; bi = oi; }
            }
            const int wid = t >> 6;
            if ((t & 63) == 0) { rv[wid] = bv; ri[wid] = bi; }
            __syncthreads();
            if (t == 0) {
                for (int wv = 1; wv < 4; ++wv)
                    if (rv[wv] > bv || (rv[wv] == bv && ri[wv] < bi)) { bv = rv[wv]; bi = ri[wv]; }
                pc_logit[(size_t)bg * 8000 + c * CN_K + it] = bv;
                pc_ind  [(size_t)bg * 8000 + c * CN_K + it] = bi;
                pick = bi;
            }
            __syncthreads();
            const int pk = pick;
            if ((pk & 255) == t) removed |= 1ull << (pk >> 8);
            __syncthreads();
        }
    }
}

// ---------------------------------------------------------------------------
// Global top-100 of 8000 via bitonic sort of 8192 keys, + sigmoid + gather.
// Key u64 = (ordered_logit << 32) | ~flat  (flat = c*100+k). One block per b.
// ---------------------------------------------------------------------------
__global__ __launch_bounds__(256) void global_out_k(
    const float* __restrict__ pc_logit, const int* __restrict__ pc_ind,
    const float* __restrict__ wh, float* __restrict__ out)
{
    constexpr int N = CN_CLS * CN_K;   // 8000
    constexpr int P = 8192;
    __shared__ unsigned long long gk[P];

    const int b = blockIdx.x;
    const int t = threadIdx.x;

    for (int n = t; n < P; n += 256) {
        unsigned long long key = 0ull;
        if (n < N) {
            const float v = pc_logit[(size_t)b * N + n];
            key = ((unsigned long long)ordf(v) << 32) | (unsigned)(~n);
        }
        gk[n] = key;
    }
    __syncthreads();

    for (int k = 2; k <= P; k <<= 1) {
        for (int j = k >> 1; j > 0; j >>= 1) {
            for (int n = t; n < (P >> 1); n += 256) {
                const int i = ((n & ~(j - 1)) << 1) | (n & (j - 1));
                const int m = i | j;
                const unsigned long long a = gk[i], bqq = gk[m];
                const bool up = ((i & k) == 0);
                if (up ? (a < bqq) : (a > bqq)) { gk[i] = bqq; gk[m] = a; }
            }
            __syncthreads();
        }
    }

    if (t < CN_K) {
        const unsigned long long key = gk[t];
        const int   flat  = (int)(~(unsigned)key) & 0x3FFF;  // < 8192
        const float logit = unordf((unsigned)(key >> 32));
        const int   cls   = flat / CN_K;
        const int   ind   = pc_ind[(size_t)b * N + flat];
        const float score = (float)(1.0 / (1.0 + exp(-(double)logit)));
        const float ys = (float)(ind >> 7) * 4.0f;
        const float xs = (float)(ind & 127) * 4.0f;
        const float wl = wh[((size_t)b * 4 + 0) * CN_HW + ind];
        const float wt = wh[((size_t)b * 4 + 1) * CN_HW + ind];
        const float wr = wh[((size_t)b * 4 + 2) * CN_HW + ind];
        const float wb = wh[((size_t)b * 4 + 3) * CN_HW + ind];
        float* row = out + ((size_t)b * CN_K + t) * 6;
        row[0] = xs - wl;
        row[1] = ys - wt;
        row[2] = xs + wr;
        row[3] = ys + wb;
        row[4] = score;
        row[5] = (float)cls;
        out[CN_B * CN_K * 6 + b * CN_K + t] = (score > 0.01f) ? 1.0f : 0.0f;
    }
}

// ---------------------------------------------------------------------------
extern "C" void kernel_launch(void* const* d_in, const int* in_sizes, int n_in,
                              void* d_out, int out_size, void* d_ws, size_t ws_size,
                              hipStream_t stream)
{
    (void)in_sizes; (void)n_in; (void)out_size;

    const float* x      = (const float*)d_in[0];
    const float* cls_w1 = (const float*)d_in[1];
    const float* cls_b1 = (const float*)d_in[2];
    const float* cls_w2 = (const float*)d_in[3];
    const float* cls_b2 = (const float*)d_in[4];
    const float* cls_w3 = (const float*)d_in[5];
    const float* cls_b3 = (const float*)d_in[6];
    const float* wh_w1  = (const float*)d_in[7];
    const float* wh_b1  = (const float*)d_in[8];
    const float* wh_w2  = (const float*)d_in[9];
    const float* wh_b2  = (const float*)d_in[10];
    const float* wh_w3  = (const float*)d_in[11];
    const float* wh_b3  = (const float*)d_in[12];
    float* out = (float*)d_out;

    const size_t PERA = 8388608u, PERB = 8388608u;
    const size_t PERS = 4194304u + 512000u + 512000u;
    int Bc = 1;
    {
        const int cand_[5] = {16, 8, 4, 2, 1};
        for (int i = 0; i < 5; ++i) {
            if ((size_t)cand_[i] * (PERA + PERB) + PERS <= ws_size) { Bc = cand_[i]; break; }
        }
    }

    char* ws = (char*)d_ws;
    char*  regA  = ws;
    char*  regB  = ws + (size_t)Bc * PERA;
    float* whbuf = (float*)(ws + (size_t)Bc * (PERA + PERB));
    float* pc_s  = (float*)((char*)whbuf + 4194304u);
    int*   pc_i  = (int*)((char*)pc_s + 512000u);

    dim3 blk(256);

    for (int b0 = 0; b0 < CN_B; b0 += Bc) {
        const float* xc = x + (size_t)b0 * 64 * CN_HW;
        float* g1     = (float*)regA;
        float* g2     = (float*)regB;
        float* h1     = (float*)regA;
        float* h2     = (float*)regB;
        float* logits = (float*)regA;
        float* whc    = whbuf + (size_t)b0 * 4 * CN_HW;

        // wh branch (f32)
        conv3x3_k<64><<<dim3(Bc * 16 * 4), blk, 0, stream>>>(xc, wh_w1, wh_b1, g1, 64);
        conv3x3_k<64><<<dim3(Bc * 16 * 4), blk, 0, stream>>>(g1, wh_w2, wh_b2, g2, 64);
        conv1x1_wh_k<<<dim3(Bc * 64), blk, 0, stream>>>(g2, wh_w3, wh_b3, whc);

        // cls branch: f32 3x3 convs (bit-identical chains), f64-accum 1x1
        conv3x3_k<64><<<dim3(Bc * 16 * 8), blk, 0, stream>>>(xc, cls_w1, cls_b1, h1, 128);
        conv3x3_k<128><<<dim3(Bc * 16 * 8), blk, 0, stream>>>(h1, cls_w2, cls_b2, h2, 128);
        conv1x1_cls_k<<<dim3(Bc * 64, 5), blk, 0, stream>>>(h2, cls_w3, cls_b3, logits);

        // per-class selection (bitonic path)
        nms_topk_k<<<dim3(Bc * CN_CLS), blk, 0, stream>>>(logits, pc_s, pc_i, b0);
    }

    global_out_k<<<dim3(CN_B), blk, 0, stream>>>(pc_s, pc_i, whbuf, out);
}